// Round 1
// 207.265 us; speedup vs baseline: 1.1818x; 1.1818x over previous
//
#include <hip/hip_runtime.h>
#include <hip/hip_bf16.h>

// Problem constants
#define B_  4
#define S_  2048
#define D_  256
#define H_  8
#define HD_ 32
#define K_  204          // int(2048 * 0.1)
#define SCALE_ 0.17677669529663687f  // 1/sqrt(32)

// ---- workspace layout (float offsets) ----
#define OFF_IMP    0          // 8192 floats
#define OFF_KG     8192       // 208896 floats [B,H,K,hd]
#define OFF_VG     217088     // 208896 floats
#define OFF_FLAGS  425984     // 8192 ints
#define OFF_KIDX   434176     // 1024 ints
#define OFF_Q      435200     // 2097152 floats [B*S, D]
#define OFF_AO     2532352    // 2097152 floats [B*S, D]
// total ~4.63M floats = 18.5 MB

// ---------------- kernel 1: gate MLP -> importance logit ----------------
__global__ __launch_bounds__(256) void gate_kernel(
    const float* __restrict__ x, const float* __restrict__ gw1,
    const float* __restrict__ gb1, const float* __restrict__ gw2, float* ws)
{
    const int t0 = blockIdx.x * 8;
    const int tid = threadIdx.x;
    __shared__ __align__(16) float xs[8 * D_];
    __shared__ float hred[8 * 64];

    const float4* src = (const float4*)(x + (size_t)t0 * D_);
    ((float4*)xs)[tid]       = src[tid];
    ((float4*)xs)[tid + 256] = src[tid + 256];
    __syncthreads();

    const int c = tid & 3, f = tid >> 2;
    float4 wv[16];
    const float4* wr = (const float4*)(gw1 + (size_t)f * D_) + c;
    #pragma unroll
    for (int j = 0; j < 16; ++j) wv[j] = wr[j * 4];
    const float bb = gb1[f], g2 = gw2[f];

    #pragma unroll
    for (int tk = 0; tk < 8; ++tk) {
        const float4* xr = (const float4*)(xs + tk * D_) + c;
        float a = 0.0f;
        #pragma unroll
        for (int j = 0; j < 16; ++j) {
            float4 xv = xr[j * 4];
            a += wv[j].x*xv.x + wv[j].y*xv.y + wv[j].z*xv.z + wv[j].w*xv.w;
        }
        a += __shfl_xor(a, 1);
        a += __shfl_xor(a, 2);
        if (c == 0) hred[tk * 64 + f] = fmaxf(a + bb, 0.0f) * g2;
    }
    __syncthreads();

    const int tk = tid >> 5, ln = tid & 31;
    float s = hred[tk * 64 + ln] + hred[tk * 64 + ln + 32];
    #pragma unroll
    for (int o = 16; o; o >>= 1) s += __shfl_xor(s, o, 32);
    if (ln == 0) ws[OFF_IMP + t0 + tk] = s;
}

// ---------------- kernel 2a: exact rank -> kept flag (lax.top_k ties) ----------------
// Re-tiled for latency: B*128 = 512 blocks. Each block ranks 16 i's; each i is
// handled by 16 consecutive lanes, each scanning a 128-j slice (32 float4 LDS
// reads) with bank-staggered order, then shfl-reduced. Exact same flag output.
__global__ __launch_bounds__(256) void rank_kernel(const float* __restrict__ ws_imp, int* flags)
{
    const int b  = blockIdx.x >> 7;        // 128 i-chunks per batch
    const int ic = blockIdx.x & 127;
    const int tid = threadIdx.x;
    __shared__ __align__(16) float vs[S_];
    const float* src = ws_imp + b * S_;
    #pragma unroll
    for (int cc = 0; cc < S_/(256*4); ++cc)
        ((float4*)vs)[tid + cc*256] = ((const float4*)src)[tid + cc*256];
    __syncthreads();

    const int il = tid >> 4;               // 0..15 : which i of this block's 16
    const int c  = tid & 15;               // 0..15 : j-slice
    const int i  = ic * 16 + il;
    const float vi = vs[i];
    int gt = 0, eq = 0;
    const float4* v4 = (const float4*)vs + c * 32;   // this slice: 128 j's
    #pragma unroll 8
    for (int t = 0; t < 32; ++t) {
        const int j4 = (t + c) & 31;       // stagger start -> spread LDS banks
        float4 w = v4[j4];
        const int base = c * 128 + j4 * 4;
        gt += (w.x > vi); eq += (w.x == vi) && (base + 0 < i);
        gt += (w.y > vi); eq += (w.y == vi) && (base + 1 < i);
        gt += (w.z > vi); eq += (w.z == vi) && (base + 2 < i);
        gt += (w.w > vi); eq += (w.w == vi) && (base + 3 < i);
    }
    int r = gt + eq;
    r += __shfl_xor(r, 1);
    r += __shfl_xor(r, 2);
    r += __shfl_xor(r, 4);
    r += __shfl_xor(r, 8);
    if (c == 0) flags[b * S_ + i] = (r < K_) ? 1 : 0;
}

// ---------------- kernel 2b: scan flags -> compact sorted index list ----------------
__global__ __launch_bounds__(256) void emit_kernel(const int* __restrict__ flags, int* kidx)
{
    const int b = blockIdx.x;
    const int t = threadIdx.x;
    __shared__ int fl[S_];
    __shared__ int cs[256];
    const int* src = flags + b * S_;
    #pragma unroll
    for (int c = 0; c < S_/256; ++c) fl[t + c*256] = src[t + c*256];
    __syncthreads();

    int s = 0;
    #pragma unroll
    for (int c = 0; c < 8; ++c) s += fl[t*8 + c];
    cs[t] = s;
    __syncthreads();
    for (int off = 1; off < 256; off <<= 1) {
        int v = (t >= off) ? cs[t - off] : 0;
        __syncthreads();
        cs[t] += v;
        __syncthreads();
    }
    int pos = cs[t] - s;
    #pragma unroll
    for (int c = 0; c < 8; ++c) {
        int idx = t*8 + c;
        if (fl[idx]) { if (pos < K_) kidx[b * K_ + pos] = idx; ++pos; }
    }
}

// ---------------- kernel 3: K/V projection for kept keys ----------------
__global__ __launch_bounds__(256) void kv_kernel(
    const float* __restrict__ x, const float* __restrict__ w_in,
    const float* __restrict__ b_in, float* ws, const int* __restrict__ kidx)
{
    const int b = blockIdx.y, j0 = blockIdx.x * 4, tid = threadIdx.x;
    __shared__ __align__(16) float xs[4 * D_];
    __shared__ int toks[4];
    if (tid < 4) {
        int tk = kidx[b * K_ + j0 + tid];
        toks[tid] = min(max(tk, 0), S_ - 1);
    }
    __syncthreads();
    {
        const int kk = tid >> 6, l = tid & 63;
        ((float4*)xs)[kk * 64 + l] =
            ((const float4*)(x + ((size_t)b * S_ + toks[kk]) * D_))[l];
    }
    __syncthreads();

    const int c = tid & 3, f = tid >> 2;
    #pragma unroll 1
    for (int fg = 0; fg < 8; ++fg) {
        const int eh = fg * 64 + f;
        float4 wv[16];
        const float4* wr = (const float4*)(w_in + (size_t)(D_ + eh) * D_) + c;
        #pragma unroll
        for (int j = 0; j < 16; ++j) wv[j] = wr[j * 4];
        float a0 = 0, a1 = 0, a2 = 0, a3 = 0;
        #pragma unroll
        for (int j = 0; j < 16; ++j) {
            float4 w = wv[j];
            float4 x0 = ((const float4*)(xs + 0*D_))[c + j*4];
            float4 x1 = ((const float4*)(xs + 1*D_))[c + j*4];
            float4 x2 = ((const float4*)(xs + 2*D_))[c + j*4];
            float4 x3 = ((const float4*)(xs + 3*D_))[c + j*4];
            a0 += w.x*x0.x + w.y*x0.y + w.z*x0.z + w.w*x0.w;
            a1 += w.x*x1.x + w.y*x1.y + w.z*x1.z + w.w*x1.w;
            a2 += w.x*x2.x + w.y*x2.y + w.z*x2.z + w.w*x2.w;
            a3 += w.x*x3.x + w.y*x3.y + w.z*x3.z + w.w*x3.w;
        }
        a0 += __shfl_xor(a0, 1); a0 += __shfl_xor(a0, 2);
        a1 += __shfl_xor(a1, 1); a1 += __shfl_xor(a1, 2);
        a2 += __shfl_xor(a2, 1); a2 += __shfl_xor(a2, 2);
        a3 += __shfl_xor(a3, 1); a3 += __shfl_xor(a3, 2);
        if (c == 0) {
            const float bias = b_in[D_ + eh];
            const int isV = eh >> 8;
            const int ee = eh & 255;
            const int h = ee >> 5, d = ee & 31;
            float* dst = ws + (isV ? OFF_VG : OFF_KG) + ((b * H_ + h) * K_) * HD_ + d;
            dst[(j0 + 0) * HD_] = a0 + bias;
            dst[(j0 + 1) * HD_] = a1 + bias;
            dst[(j0 + 2) * HD_] = a2 + bias;
            dst[(j0 + 3) * HD_] = a3 + bias;
        }
    }
}

// ---------------- kernel 4: tiled fp32 GEMM  C[M,256] = A[M,256] * W[256,256]^T + bias ----------------
// W row-major [n][k] (torch Linear layout). BM=BN=64, BK=32, 4x4 microtile.
__global__ __launch_bounds__(256) void gemm_kernel(
    const float* __restrict__ A, const float* __restrict__ W,
    const float* __restrict__ bias, float* __restrict__ C)
{
    const int m0 = blockIdx.x * 64;
    const int n0 = blockIdx.y * 64;
    const int tid = threadIdx.x;
    __shared__ __align__(16) float As[32 * 68];
    __shared__ __align__(16) float Bs[32 * 68];
    const int tm = tid & 15, tn = tid >> 4;
    const int row = tid >> 3, dc = tid & 7;

    float4 acc0 = {0,0,0,0}, acc1 = {0,0,0,0}, acc2 = {0,0,0,0}, acc3 = {0,0,0,0};

    for (int k0 = 0; k0 < D_; k0 += 32) {
        float4 a0 = *(const float4*)(A + (size_t)(m0 + row) * D_ + k0 + dc * 4);
        float4 a1 = *(const float4*)(A + (size_t)(m0 + row + 32) * D_ + k0 + dc * 4);
        float4 w0 = *(const float4*)(W + (size_t)(n0 + row) * D_ + k0 + dc * 4);
        float4 w1 = *(const float4*)(W + (size_t)(n0 + row + 32) * D_ + k0 + dc * 4);
        __syncthreads();
        As[(dc*4+0)*68 + row] = a0.x; As[(dc*4+1)*68 + row] = a0.y;
        As[(dc*4+2)*68 + row] = a0.z; As[(dc*4+3)*68 + row] = a0.w;
        As[(dc*4+0)*68 + row+32] = a1.x; As[(dc*4+1)*68 + row+32] = a1.y;
        As[(dc*4+2)*68 + row+32] = a1.z; As[(dc*4+3)*68 + row+32] = a1.w;
        Bs[(dc*4+0)*68 + row] = w0.x; Bs[(dc*4+1)*68 + row] = w0.y;
        Bs[(dc*4+2)*68 + row] = w0.z; Bs[(dc*4+3)*68 + row] = w0.w;
        Bs[(dc*4+0)*68 + row+32] = w1.x; Bs[(dc*4+1)*68 + row+32] = w1.y;
        Bs[(dc*4+2)*68 + row+32] = w1.z; Bs[(dc*4+3)*68 + row+32] = w1.w;
        __syncthreads();
        #pragma unroll
        for (int k = 0; k < 32; ++k) {
            float4 a4 = *(const float4*)&As[k*68 + tm*4];
            float4 b4 = *(const float4*)&Bs[k*68 + tn*4];
            acc0.x += a4.x*b4.x; acc0.y += a4.x*b4.y; acc0.z += a4.x*b4.z; acc0.w += a4.x*b4.w;
            acc1.x += a4.y*b4.x; acc1.y += a4.y*b4.y; acc1.z += a4.y*b4.z; acc1.w += a4.y*b4.w;
            acc2.x += a4.z*b4.x; acc2.y += a4.z*b4.y; acc2.z += a4.z*b4.z; acc2.w += a4.z*b4.w;
            acc3.x += a4.w*b4.x; acc3.y += a4.w*b4.y; acc3.z += a4.w*b4.z; acc3.w += a4.w*b4.w;
        }
    }
    float4 bi = *(const float4*)(bias + n0 + tn*4);
    float4 o;
    o.x = acc0.x+bi.x; o.y = acc0.y+bi.y; o.z = acc0.z+bi.z; o.w = acc0.w+bi.w;
    *(float4*)(C + (size_t)(m0 + tm*4 + 0) * D_ + n0 + tn*4) = o;
    o.x = acc1.x+bi.x; o.y = acc1.y+bi.y; o.z = acc1.z+bi.z; o.w = acc1.w+bi.w;
    *(float4*)(C + (size_t)(m0 + tm*4 + 1) * D_ + n0 + tn*4) = o;
    o.x = acc2.x+bi.x; o.y = acc2.y+bi.y; o.z = acc2.z+bi.z; o.w = acc2.w+bi.w;
    *(float4*)(C + (size_t)(m0 + tm*4 + 2) * D_ + n0 + tn*4) = o;
    o.x = acc3.x+bi.x; o.y = acc3.y+bi.y; o.z = acc3.z+bi.z; o.w = acc3.w+bi.w;
    *(float4*)(C + (size_t)(m0 + tm*4 + 3) * D_ + n0 + tn*4) = o;
}

// ---------------- kernel 5: attention core ----------------
// one block per (32-query tile, head, batch). K/V/Q staged in LDS once.
__global__ __launch_bounds__(256) void attn_kernel(const float* __restrict__ ws, float* __restrict__ ao)
{
    const int b = blockIdx.z, h = blockIdx.y, q0 = blockIdx.x * 32;
    const int tid = threadIdx.x;
    __shared__ __align__(16) float Kt[32 * 212];   // Kt[d][j]; later overlaid by Ss[j][q]
    __shared__ __align__(16) float Vs[K_ * 32];    // Vs[j][d]
    __shared__ __align__(16) float Qt[32 * 36];    // Qt[d][q]
    __shared__ __align__(16) float Ored[4 * 32 * 32];
    __shared__ float red[8 * 32];
    __shared__ float inv[32];

    const float4* kg = (const float4*)(ws + OFF_KG + ((b * H_ + h) * K_) * HD_);
    const float4* vg = (const float4*)(ws + OFF_VG + ((b * H_ + h) * K_) * HD_);

    for (int i = tid; i < K_ * 8; i += 256) ((float4*)Vs)[i] = vg[i];
    for (int i = tid; i < K_ * 8; i += 256) {
        const int j = i >> 3, dc = i & 7;
        float4 kv = kg[i];
        Kt[(dc*4+0)*212 + j] = kv.x;
        Kt[(dc*4+1)*212 + j] = kv.y;
        Kt[(dc*4+2)*212 + j] = kv.z;
        Kt[(dc*4+3)*212 + j] = kv.w;
    }
    {
        const int q = tid >> 3, dc = tid & 7;
        float4 qv = *(const float4*)(ws + OFF_Q + (size_t)(b * S_ + q0 + q) * D_ + h * HD_ + dc * 4);
        Qt[(dc*4+0)*36 + q] = qv.x;
        Qt[(dc*4+1)*36 + q] = qv.y;
        Qt[(dc*4+2)*36 + q] = qv.z;
        Qt[(dc*4+3)*36 + q] = qv.w;
    }
    __syncthreads();

    // ---- scores: virtual threads w = p*256+tid; jg in [0,51), qg in [0,8) ----
    // acc[jj] is a float4 over 4 q's. exp applied in-register (scores bounded, no max needed:
    // identical math to softmax-with-max up to rounding since exp(s-m)/sum = exp(s)/sum).
    float4 e0[4], e1[4];
    {
        const int jg = tid >> 3, qg = tid & 7;
        float4 a0 = {0,0,0,0}, a1 = {0,0,0,0}, a2 = {0,0,0,0}, a3 = {0,0,0,0};
        #pragma unroll 8
        for (int d = 0; d < 32; ++d) {
            float4 kf = *(const float4*)&Kt[d*212 + jg*4];
            float4 qf = *(const float4*)&Qt[d*36 + qg*4];
            a0.x += kf.x*qf.x; a0.y += kf.x*qf.y; a0.z += kf.x*qf.z; a0.w += kf.x*qf.w;
            a1.x += kf.y*qf.x; a1.y += kf.y*qf.y; a1.z += kf.y*qf.z; a1.w += kf.y*qf.w;
            a2.x += kf.z*qf.x; a2.y += kf.z*qf.y; a2.z += kf.z*qf.z; a2.w += kf.z*qf.w;
            a3.x += kf.w*qf.x; a3.y += kf.w*qf.y; a3.z += kf.w*qf.z; a3.w += kf.w*qf.w;
        }
        e0[0].x = __expf(a0.x*SCALE_); e0[0].y = __expf(a0.y*SCALE_); e0[0].z = __expf(a0.z*SCALE_); e0[0].w = __expf(a0.w*SCALE_);
        e0[1].x = __expf(a1.x*SCALE_); e0[1].y = __expf(a1.y*SCALE_); e0[1].z = __expf(a1.z*SCALE_); e0[1].w = __expf(a1.w*SCALE_);
        e0[2].x = __expf(a2.x*SCALE_); e0[2].y = __expf(a2.y*SCALE_); e0[2].z = __expf(a2.z*SCALE_); e0[2].w = __expf(a2.w*SCALE_);
        e0[3].x = __expf(a3.x*SCALE_); e0[3].y = __expf(a3.y*SCALE_); e0[3].z = __expf(a3.z*SCALE_); e0[3].w = __expf(a3.w*SCALE_);
    }
    if (tid < 152) {
        const int w = 256 + tid;
        const int jg = w >> 3, qg = w & 7;
        float4 a0 = {0,0,0,0}, a1 = {0,0,0,0}, a2 = {0,0,0,0}, a3 = {0,0,0,0};
        #pragma unroll 8
        for (int d = 0; d < 32; ++d) {
            float4 kf = *(const float4*)&Kt[d*212 + jg*4];
            float4 qf = *(const float4*)&Qt[d*36 + qg*4];
            a0.x += kf.x*qf.x; a0.y += kf.x*qf.y; a0.z += kf.x*qf.z; a0.w += kf.x*qf.w;
            a1.x += kf.y*qf.x; a1.y += kf.y*qf.y; a1.z += kf.y*qf.z; a1.w += kf.y*qf.w;
            a2.x += kf.z*qf.x; a2.y += kf.z*qf.y; a2.z += kf.z*qf.z; a2.w += kf.z*qf.w;
            a3.x += kf.w*qf.x; a3.y += kf.w*qf.y; a3.z += kf.w*qf.z; a3.w += kf.w*qf.w;
        }
        e1[0].x = __expf(a0.x*SCALE_); e1[0].y = __expf(a0.y*SCALE_); e1[0].z = __expf(a0.z*SCALE_); e1[0].w = __expf(a0.w*SCALE_);
        e1[1].x = __expf(a1.x*SCALE_); e1[1].y = __expf(a1.y*SCALE_); e1[1].z = __expf(a1.z*SCALE_); e1[1].w = __expf(a1.w*SCALE_);
        e1[2].x = __expf(a2.x*SCALE_); e1[2].y = __expf(a2.y*SCALE_); e1[2].z = __expf(a2.z*SCALE_); e1[2].w = __expf(a2.w*SCALE_);
        e1[3].x = __expf(a3.x*SCALE_); e1[3].y = __expf(a3.y*SCALE_); e1[3].z = __expf(a3.z*SCALE_); e1[3].w = __expf(a3.w*SCALE_);
    }
    __syncthreads();   // all Kt reads complete before overlay

    float* Ss = Kt;    // Ss[j*32 + q], 6528 floats <= Kt's 6784
    {
        const int jg = tid >> 3, qg = tid & 7;
        *(float4*)&Ss[(jg*4+0)*32 + qg*4] = e0[0];
        *(float4*)&Ss[(jg*4+1)*32 + qg*4] = e0[1];
        *(float4*)&Ss[(jg*4+2)*32 + qg*4] = e0[2];
        *(float4*)&Ss[(jg*4+3)*32 + qg*4] = e0[3];
    }
    if (tid < 152) {
        const int w = 256 + tid;
        const int jg = w >> 3, qg = w & 7;
        *(float4*)&Ss[(jg*4+0)*32 + qg*4] = e1[0];
        *(float4*)&Ss[(jg*4+1)*32 + qg*4] = e1[1];
        *(float4*)&Ss[(jg*4+2)*32 + qg*4] = e1[2];
        *(float4*)&Ss[(jg*4+3)*32 + qg*4] = e1[3];
    }
    __syncthreads();

    // ---- softmax denominator ----
    {
        const int q = tid & 31, l = tid >> 5;
        float s = 0.0f;
        const int nt = (l < 4) ? 26 : 25;
        for (int t = 0; t < nt; ++t) s += Ss[(l + 8*t)*32 + q];
        red[l*32 + q] = s;
    }
    __syncthreads();
    if (tid < 32) {
        float s = 0.0f;
        #pragma unroll
        for (int l = 0; l < 8; ++l) s += red[l*32 + tid];
        inv[tid] = 1.0f / s;
    }
    __syncthreads();

    // ---- PV: wave w handles j in [51w, 51w+51); thread=(qg,dg) covers 4q x 4d ----
    {
        const int wv = tid >> 6, lane = tid & 63;
        const int qg = lane >> 3, dg = lane & 7;
        float4 c0 = {0,0,0,0}, c1 = {0,0,0,0}, c2 = {0,0,0,0}, c3 = {0,0,0,0};
        const int j0 = wv * 51;
        for (int j = j0; j < j0 + 51; ++j) {
            float4 sf = *(const float4*)&Ss[j*32 + qg*4];
            float4 vf = *(const float4*)&Vs[j*32 + dg*4];
            c0.x += sf.x*vf.x; c0.y += sf.x*vf.y; c0.z += sf.x*vf.z; c0.w += sf.x*vf.w;
            c1.x += sf.y*vf.x; c1.y += sf.y*vf.y; c1.z += sf.y*vf.z; c1.w += sf.y*vf.w;
            c2.x += sf.z*vf.x; c2.y += sf.z*vf.y; c2.z += sf.z*vf.z; c2.w += sf.z*vf.w;
            c3.x += sf.w*vf.x; c3.y += sf.w*vf.y; c3.z += sf.w*vf.z; c3.w += sf.w*vf.w;
        }
        *(float4*)&Ored[wv*1024 + (qg*4+0)*32 + dg*4] = c0;
        *(float4*)&Ored[wv*1024 + (qg*4+1)*32 + dg*4] = c1;
        *(float4*)&Ored[wv*1024 + (qg*4+2)*32 + dg*4] = c2;
        *(float4*)&Ored[wv*1024 + (qg*4+3)*32 + dg*4] = c3;
    }
    __syncthreads();
    {
        const int q = tid >> 3, dg = tid & 7;
        float4 o = {0,0,0,0};
        #pragma unroll
        for (int w = 0; w < 4; ++w) {
            float4 t = *(const float4*)&Ored[w*1024 + q*32 + dg*4];
            o.x += t.x; o.y += t.y; o.z += t.z; o.w += t.w;
        }
        const float iv = inv[q];
        float4 r; r.x = o.x*iv; r.y = o.y*iv; r.z = o.z*iv; r.w = o.w*iv;
        *(float4*)(ao + (size_t)(b * S_ + q0 + q) * D_ + h * HD_ + dg * 4) = r;
    }
}

extern "C" void kernel_launch(void* const* d_in, const int* in_sizes, int n_in,
                              void* d_out, int out_size, void* d_ws, size_t ws_size,
                              hipStream_t stream)
{
    const float* x     = (const float*)d_in[0];
    const float* w_in  = (const float*)d_in[1];
    const float* b_in  = (const float*)d_in[2];
    const float* w_out = (const float*)d_in[3];
    const float* b_out = (const float*)d_in[4];
    const float* gw1   = (const float*)d_in[5];
    const float* gb1   = (const float*)d_in[6];
    const float* gw2   = (const float*)d_in[7];
    // d_in[8] = gate_b2: constant inside monotone sigmoid -> doesn't affect top-k

    float* ws = (float*)d_ws;
    int* flags = (int*)(ws + OFF_FLAGS);
    int* kidx  = (int*)(ws + OFF_KIDX);
    float* out = (float*)d_out;

    gate_kernel<<<B_ * S_ / 8, 256, 0, stream>>>(x, gw1, gb1, gw2, ws);
    rank_kernel<<<B_ * 128, 256, 0, stream>>>(ws + OFF_IMP, flags);
    emit_kernel<<<B_, 256, 0, stream>>>(flags, kidx);
    kv_kernel<<<dim3(51, B_), 256, 0, stream>>>(x, w_in, b_in, ws, kidx);
    // Q = x @ w_in[0:256]^T + b_in[0:256]
    gemm_kernel<<<dim3(B_ * S_ / 64, D_ / 64), 256, 0, stream>>>(x, w_in, b_in, ws + OFF_Q);
    attn_kernel<<<dim3(S_ / 32, H_, B_), 256, 0, stream>>>(ws, ws + OFF_AO);
    // out = AO @ w_out^T + b_out
    gemm_kernel<<<dim3(B_ * S_ / 64, D_ / 64), 256, 0, stream>>>(ws + OFF_AO, w_out, b_out, out);
}

// Round 2
// 185.727 us; speedup vs baseline: 1.3189x; 1.1160x over previous
//
#include <hip/hip_runtime.h>
#include <hip/hip_bf16.h>

// Problem constants
#define B_  4
#define S_  2048
#define D_  256
#define H_  8
#define HD_ 32
#define K_  204          // int(2048 * 0.1)
#define SCALE_ 0.17677669529663687f  // 1/sqrt(32)

// ---- workspace layout (float offsets) ----
#define OFF_IMP    0          // 8192 floats
#define OFF_KG     8192       // 208896 floats [B,H,K,hd]
#define OFF_VG     217088     // 208896 floats
#define OFF_FLAGS  425984     // 8192 ints
#define OFF_KIDX   434176     // 1024 ints
#define OFF_Q      435200     // 2097152 floats [B*S, D]
#define OFF_AO     2532352    // 2097152 floats [B*S, D]
// total ~4.63M floats = 18.5 MB

// ---------------- kernel 1: gate MLP -> importance logit ----------------
__global__ __launch_bounds__(256) void gate_kernel(
    const float* __restrict__ x, const float* __restrict__ gw1,
    const float* __restrict__ gb1, const float* __restrict__ gw2, float* ws)
{
    const int t0 = blockIdx.x * 8;
    const int tid = threadIdx.x;
    __shared__ __align__(16) float xs[8 * D_];
    __shared__ float hred[8 * 64];

    const float4* src = (const float4*)(x + (size_t)t0 * D_);
    ((float4*)xs)[tid]       = src[tid];
    ((float4*)xs)[tid + 256] = src[tid + 256];
    __syncthreads();

    const int c = tid & 3, f = tid >> 2;
    float4 wv[16];
    const float4* wr = (const float4*)(gw1 + (size_t)f * D_) + c;
    #pragma unroll
    for (int j = 0; j < 16; ++j) wv[j] = wr[j * 4];
    const float bb = gb1[f], g2 = gw2[f];

    #pragma unroll
    for (int tk = 0; tk < 8; ++tk) {
        const float4* xr = (const float4*)(xs + tk * D_) + c;
        float a = 0.0f;
        #pragma unroll
        for (int j = 0; j < 16; ++j) {
            float4 xv = xr[j * 4];
            a += wv[j].x*xv.x + wv[j].y*xv.y + wv[j].z*xv.z + wv[j].w*xv.w;
        }
        a += __shfl_xor(a, 1);
        a += __shfl_xor(a, 2);
        if (c == 0) hred[tk * 64 + f] = fmaxf(a + bb, 0.0f) * g2;
    }
    __syncthreads();

    const int tk = tid >> 5, ln = tid & 31;
    float s = hred[tk * 64 + ln] + hred[tk * 64 + ln + 32];
    #pragma unroll
    for (int o = 16; o; o >>= 1) s += __shfl_xor(s, o, 32);
    if (ln == 0) ws[OFF_IMP + t0 + tk] = s;
}

// ---------------- kernel 2a: exact rank -> kept flag (lax.top_k ties) ----------------
__global__ __launch_bounds__(256) void rank_kernel(const float* __restrict__ ws_imp, int* flags)
{
    const int b  = blockIdx.x >> 7;        // 128 i-chunks per batch
    const int ic = blockIdx.x & 127;
    const int tid = threadIdx.x;
    __shared__ __align__(16) float vs[S_];
    const float* src = ws_imp + b * S_;
    #pragma unroll
    for (int cc = 0; cc < S_/(256*4); ++cc)
        ((float4*)vs)[tid + cc*256] = ((const float4*)src)[tid + cc*256];
    __syncthreads();

    const int il = tid >> 4;               // 0..15 : which i of this block's 16
    const int c  = tid & 15;               // 0..15 : j-slice
    const int i  = ic * 16 + il;
    const float vi = vs[i];
    int gt = 0, eq = 0;
    const float4* v4 = (const float4*)vs + c * 32;   // this slice: 128 j's
    #pragma unroll 8
    for (int t = 0; t < 32; ++t) {
        const int j4 = (t + c) & 31;       // stagger start -> spread LDS banks
        float4 w = v4[j4];
        const int base = c * 128 + j4 * 4;
        gt += (w.x > vi); eq += (w.x == vi) && (base + 0 < i);
        gt += (w.y > vi); eq += (w.y == vi) && (base + 1 < i);
        gt += (w.z > vi); eq += (w.z == vi) && (base + 2 < i);
        gt += (w.w > vi); eq += (w.w == vi) && (base + 3 < i);
    }
    int r = gt + eq;
    r += __shfl_xor(r, 1);
    r += __shfl_xor(r, 2);
    r += __shfl_xor(r, 4);
    r += __shfl_xor(r, 8);
    if (c == 0) flags[b * S_ + i] = (r < K_) ? 1 : 0;
}

// ---------------- kernel 2b: scan flags -> compact sorted index list ----------------
__global__ __launch_bounds__(256) void emit_kernel(const int* __restrict__ flags, int* kidx)
{
    const int b = blockIdx.x;
    const int t = threadIdx.x;
    __shared__ int fl[S_];
    __shared__ int cs[256];
    const int* src = flags + b * S_;
    #pragma unroll
    for (int c = 0; c < S_/256; ++c) fl[t + c*256] = src[t + c*256];
    __syncthreads();

    int s = 0;
    #pragma unroll
    for (int c = 0; c < 8; ++c) s += fl[t*8 + c];
    cs[t] = s;
    __syncthreads();
    for (int off = 1; off < 256; off <<= 1) {
        int v = (t >= off) ? cs[t - off] : 0;
        __syncthreads();
        cs[t] += v;
        __syncthreads();
    }
    int pos = cs[t] - s;
    #pragma unroll
    for (int c = 0; c < 8; ++c) {
        int idx = t*8 + c;
        if (fl[idx]) { if (pos < K_) kidx[b * K_ + pos] = idx; ++pos; }
    }
}

// ---------------- kernel 3: K/V projection for kept keys ----------------
__global__ __launch_bounds__(256) void kv_kernel(
    const float* __restrict__ x, const float* __restrict__ w_in,
    const float* __restrict__ b_in, float* ws, const int* __restrict__ kidx)
{
    const int b = blockIdx.y, j0 = blockIdx.x * 4, tid = threadIdx.x;
    __shared__ __align__(16) float xs[4 * D_];
    __shared__ int toks[4];
    if (tid < 4) {
        int tk = kidx[b * K_ + j0 + tid];
        toks[tid] = min(max(tk, 0), S_ - 1);
    }
    __syncthreads();
    {
        const int kk = tid >> 6, l = tid & 63;
        ((float4*)xs)[kk * 64 + l] =
            ((const float4*)(x + ((size_t)b * S_ + toks[kk]) * D_))[l];
    }
    __syncthreads();

    const int c = tid & 3, f = tid >> 2;
    #pragma unroll 1
    for (int fg = 0; fg < 8; ++fg) {
        const int eh = fg * 64 + f;
        float4 wv[16];
        const float4* wr = (const float4*)(w_in + (size_t)(D_ + eh) * D_) + c;
        #pragma unroll
        for (int j = 0; j < 16; ++j) wv[j] = wr[j * 4];
        float a0 = 0, a1 = 0, a2 = 0, a3 = 0;
        #pragma unroll
        for (int j = 0; j < 16; ++j) {
            float4 w = wv[j];
            float4 x0 = ((const float4*)(xs + 0*D_))[c + j*4];
            float4 x1 = ((const float4*)(xs + 1*D_))[c + j*4];
            float4 x2 = ((const float4*)(xs + 2*D_))[c + j*4];
            float4 x3 = ((const float4*)(xs + 3*D_))[c + j*4];
            a0 += w.x*x0.x + w.y*x0.y + w.z*x0.z + w.w*x0.w;
            a1 += w.x*x1.x + w.y*x1.y + w.z*x1.z + w.w*x1.w;
            a2 += w.x*x2.x + w.y*x2.y + w.z*x2.z + w.w*x2.w;
            a3 += w.x*x3.x + w.y*x3.y + w.z*x3.z + w.w*x3.w;
        }
        a0 += __shfl_xor(a0, 1); a0 += __shfl_xor(a0, 2);
        a1 += __shfl_xor(a1, 1); a1 += __shfl_xor(a1, 2);
        a2 += __shfl_xor(a2, 1); a2 += __shfl_xor(a2, 2);
        a3 += __shfl_xor(a3, 1); a3 += __shfl_xor(a3, 2);
        if (c == 0) {
            const float bias = b_in[D_ + eh];
            const int isV = eh >> 8;
            const int ee = eh & 255;
            const int h = ee >> 5, d = ee & 31;
            float* dst = ws + (isV ? OFF_VG : OFF_KG) + ((b * H_ + h) * K_) * HD_ + d;
            dst[(j0 + 0) * HD_] = a0 + bias;
            dst[(j0 + 1) * HD_] = a1 + bias;
            dst[(j0 + 2) * HD_] = a2 + bias;
            dst[(j0 + 3) * HD_] = a3 + bias;
        }
    }
}

// ---------------- kernel 4: tiled fp32 GEMM  C[M,256] = A[M,256] * W[256,256]^T + bias ----------------
__global__ __launch_bounds__(256) void gemm_kernel(
    const float* __restrict__ A, const float* __restrict__ W,
    const float* __restrict__ bias, float* __restrict__ C)
{
    const int m0 = blockIdx.x * 64;
    const int n0 = blockIdx.y * 64;
    const int tid = threadIdx.x;
    __shared__ __align__(16) float As[32 * 68];
    __shared__ __align__(16) float Bs[32 * 68];
    const int tm = tid & 15, tn = tid >> 4;
    const int row = tid >> 3, dc = tid & 7;

    float4 acc0 = {0,0,0,0}, acc1 = {0,0,0,0}, acc2 = {0,0,0,0}, acc3 = {0,0,0,0};

    for (int k0 = 0; k0 < D_; k0 += 32) {
        float4 a0 = *(const float4*)(A + (size_t)(m0 + row) * D_ + k0 + dc * 4);
        float4 a1 = *(const float4*)(A + (size_t)(m0 + row + 32) * D_ + k0 + dc * 4);
        float4 w0 = *(const float4*)(W + (size_t)(n0 + row) * D_ + k0 + dc * 4);
        float4 w1 = *(const float4*)(W + (size_t)(n0 + row + 32) * D_ + k0 + dc * 4);
        __syncthreads();
        As[(dc*4+0)*68 + row] = a0.x; As[(dc*4+1)*68 + row] = a0.y;
        As[(dc*4+2)*68 + row] = a0.z; As[(dc*4+3)*68 + row] = a0.w;
        As[(dc*4+0)*68 + row+32] = a1.x; As[(dc*4+1)*68 + row+32] = a1.y;
        As[(dc*4+2)*68 + row+32] = a1.z; As[(dc*4+3)*68 + row+32] = a1.w;
        Bs[(dc*4+0)*68 + row] = w0.x; Bs[(dc*4+1)*68 + row] = w0.y;
        Bs[(dc*4+2)*68 + row] = w0.z; Bs[(dc*4+3)*68 + row] = w0.w;
        Bs[(dc*4+0)*68 + row+32] = w1.x; Bs[(dc*4+1)*68 + row+32] = w1.y;
        Bs[(dc*4+2)*68 + row+32] = w1.z; Bs[(dc*4+3)*68 + row+32] = w1.w;
        __syncthreads();
        #pragma unroll
        for (int k = 0; k < 32; ++k) {
            float4 a4 = *(const float4*)&As[k*68 + tm*4];
            float4 b4 = *(const float4*)&Bs[k*68 + tn*4];
            acc0.x += a4.x*b4.x; acc0.y += a4.x*b4.y; acc0.z += a4.x*b4.z; acc0.w += a4.x*b4.w;
            acc1.x += a4.y*b4.x; acc1.y += a4.y*b4.y; acc1.z += a4.y*b4.z; acc1.w += a4.y*b4.w;
            acc2.x += a4.z*b4.x; acc2.y += a4.z*b4.y; acc2.z += a4.z*b4.z; acc2.w += a4.z*b4.w;
            acc3.x += a4.w*b4.x; acc3.y += a4.w*b4.y; acc3.z += a4.w*b4.z; acc3.w += a4.w*b4.w;
        }
    }
    float4 bi = *(const float4*)(bias + n0 + tn*4);
    float4 o;
    o.x = acc0.x+bi.x; o.y = acc0.y+bi.y; o.z = acc0.z+bi.z; o.w = acc0.w+bi.w;
    *(float4*)(C + (size_t)(m0 + tm*4 + 0) * D_ + n0 + tn*4) = o;
    o.x = acc1.x+bi.x; o.y = acc1.y+bi.y; o.z = acc1.z+bi.z; o.w = acc1.w+bi.w;
    *(float4*)(C + (size_t)(m0 + tm*4 + 1) * D_ + n0 + tn*4) = o;
    o.x = acc2.x+bi.x; o.y = acc2.y+bi.y; o.z = acc2.z+bi.z; o.w = acc2.w+bi.w;
    *(float4*)(C + (size_t)(m0 + tm*4 + 2) * D_ + n0 + tn*4) = o;
    o.x = acc3.x+bi.x; o.y = acc3.y+bi.y; o.z = acc3.z+bi.z; o.w = acc3.w+bi.w;
    *(float4*)(C + (size_t)(m0 + tm*4 + 3) * D_ + n0 + tn*4) = o;
}

// ---------------- kernel 5: attention core (MFMA bf16, fp32 accum) ----------------
// One block per (32-query tile, head, batch); 4 waves.
// QK^T: A=Q (16x32), B=K^T (32x16), 13 j-tiles (204 -> pad 208), fp32 scores.
// exp in fp32, P (bf16) + V^T (bf16) in LDS, PV computes O^T = V^T * P^T:
// each wave owns one 16x16 output quadrant (no cross-wave reduce).
#define PSTR 228   // P row stride (bf16 elems), odd-word -> conflict-free writes
#define VSTR 228   // V^T row stride

typedef __attribute__((ext_vector_type(8))) short short8v;
typedef __attribute__((ext_vector_type(4))) float f32x4;

static __device__ __forceinline__ unsigned short f2bf(float f) {
    unsigned int u = __float_as_uint(f);
    u += 0x7FFFu + ((u >> 16) & 1u);      // round-to-nearest-even
    return (unsigned short)(u >> 16);
}
static __device__ __forceinline__ short8v pack_bf8(float4 a, float4 b) {
    short8v r;
    r[0]=(short)f2bf(a.x); r[1]=(short)f2bf(a.y); r[2]=(short)f2bf(a.z); r[3]=(short)f2bf(a.w);
    r[4]=(short)f2bf(b.x); r[5]=(short)f2bf(b.y); r[6]=(short)f2bf(b.z); r[7]=(short)f2bf(b.w);
    return r;
}
static __device__ __forceinline__ short8v ld_bf8(const unsigned short* p) {
    // 8B-aligned LDS source: two ds_read_b64
    union { unsigned int u[4]; short8v v; } cv;
    const uint2 a  = *(const uint2*)(p);
    const uint2 b2 = *(const uint2*)(p + 4);
    cv.u[0] = a.x; cv.u[1] = a.y; cv.u[2] = b2.x; cv.u[3] = b2.y;
    return cv.v;
}

__global__ __launch_bounds__(256) void attn_kernel(const float* __restrict__ ws, float* __restrict__ ao)
{
    const int b = blockIdx.z, h = blockIdx.y, q0 = blockIdx.x * 32;
    const int tid = threadIdx.x;
    const int lane = tid & 63, w = tid >> 6;
    const int c = lane & 15, g = lane >> 4;

    __shared__ __align__(16) unsigned short Pl[32 * PSTR];    // P[q][j] bf16
    __shared__ __align__(16) unsigned short VTl[32 * VSTR];   // V^T[d][j] bf16
    __shared__ float redl[4 * 32];
    __shared__ float invl[32];

    const float* KGb = ws + OFF_KG + (size_t)(b * H_ + h) * K_ * HD_;
    const float* VGb = ws + OFF_VG + (size_t)(b * H_ + h) * K_ * HD_;

    // ---- stage V^T (bf16) into LDS; zero pad regions ----
    for (int i = tid; i < K_ * 8; i += 256) {
        const int j = i >> 3, dc = i & 7;
        const float4 v = ((const float4*)VGb)[i];
        VTl[(dc*4+0)*VSTR + j] = f2bf(v.x);
        VTl[(dc*4+1)*VSTR + j] = f2bf(v.y);
        VTl[(dc*4+2)*VSTR + j] = f2bf(v.z);
        VTl[(dc*4+3)*VSTR + j] = f2bf(v.w);
    }
    {   // P pad: j = 208..223 for all 32 q rows (32 q x 8 chunks of 2 cols)
        const int q = tid >> 3, cc = tid & 7;
        *(unsigned int*)&Pl[q * PSTR + 208 + cc * 2] = 0u;
    }
    for (int i = tid; i < 32 * 20; i += 256) {   // VT pad: j = 204..223
        VTl[(i / 20) * VSTR + 204 + (i % 20)] = 0;
    }

    // ---- QK^T via MFMA: wave w handles j-tiles {w, w+4, w+8, (w+12)} ----
    short8v qa[2];
    #pragma unroll
    for (int qt = 0; qt < 2; ++qt) {
        const float* qp = ws + OFF_Q + (size_t)(b * S_ + q0 + qt*16 + c) * D_ + h * HD_ + g * 8;
        qa[qt] = pack_bf8(*(const float4*)qp, *(const float4*)(qp + 4));
    }
    const int njt = (w == 0) ? 4 : 3;
    f32x4 acc[2][4];
    const f32x4 zf = {0.0f, 0.0f, 0.0f, 0.0f};
    #pragma unroll
    for (int qt = 0; qt < 2; ++qt)
        #pragma unroll
        for (int t = 0; t < 4; ++t) acc[qt][t] = zf;

    for (int t = 0; t < njt; ++t) {
        const int jt = w + 4 * t;
        const int jc = min(jt * 16 + c, K_ - 1);
        const float* kp = KGb + (size_t)jc * HD_ + g * 8;
        const short8v kb = pack_bf8(*(const float4*)kp, *(const float4*)(kp + 4));
        acc[0][t] = __builtin_amdgcn_mfma_f32_16x16x32_bf16(qa[0], kb, acc[0][t], 0, 0, 0);
        acc[1][t] = __builtin_amdgcn_mfma_f32_16x16x32_bf16(qa[1], kb, acc[1][t], 0, 0, 0);
    }

    // exp (fp32), write P (bf16), accumulate row-sums
    float rs[2][4] = {{0,0,0,0},{0,0,0,0}};
    for (int t = 0; t < njt; ++t) {
        const int jg = (w + 4 * t) * 16 + c;
        const bool val = (jg < K_);
        #pragma unroll
        for (int qt = 0; qt < 2; ++qt) {
            #pragma unroll
            for (int r = 0; r < 4; ++r) {
                const float e = val ? __expf(acc[qt][t][r] * SCALE_) : 0.0f;
                rs[qt][r] += e;
                Pl[(qt*16 + g*4 + r) * PSTR + jg] = f2bf(e);
            }
        }
    }
    #pragma unroll
    for (int qt = 0; qt < 2; ++qt)
        #pragma unroll
        for (int r = 0; r < 4; ++r) {
            float s = rs[qt][r];
            s += __shfl_xor(s, 1); s += __shfl_xor(s, 2);
            s += __shfl_xor(s, 4); s += __shfl_xor(s, 8);
            if (c == 0) redl[w * 32 + qt*16 + g*4 + r] = s;
        }

    __syncthreads();
    if (tid < 32)
        invl[tid] = 1.0f / (redl[tid] + redl[32 + tid] + redl[64 + tid] + redl[96 + tid]);
    __syncthreads();

    // ---- PV: O^T = V^T * P^T; wave w -> quadrant (dt = w>>1, qt2 = w&1) ----
    const int dt = w >> 1, qt2 = w & 1;
    f32x4 o = zf;
    const unsigned short* vb = &VTl[(dt*16 + c) * VSTR];
    const unsigned short* pb = &Pl[(qt2*16 + c) * PSTR];
    #pragma unroll
    for (int kt = 0; kt < 7; ++kt) {
        const short8v av = ld_bf8(vb + kt*32 + g*8);
        const short8v bv = ld_bf8(pb + kt*32 + g*8);
        o = __builtin_amdgcn_mfma_f32_16x16x32_bf16(av, bv, o, 0, 0, 0);
    }
    const float iv = invl[qt2*16 + c];
    float4 r4; r4.x = o[0]*iv; r4.y = o[1]*iv; r4.z = o[2]*iv; r4.w = o[3]*iv;
    *(float4*)(ao + (size_t)(b * S_ + q0 + qt2*16 + c) * D_ + h * HD_ + dt*16 + g*4) = r4;
}

extern "C" void kernel_launch(void* const* d_in, const int* in_sizes, int n_in,
                              void* d_out, int out_size, void* d_ws, size_t ws_size,
                              hipStream_t stream)
{
    const float* x     = (const float*)d_in[0];
    const float* w_in  = (const float*)d_in[1];
    const float* b_in  = (const float*)d_in[2];
    const float* w_out = (const float*)d_in[3];
    const float* b_out = (const float*)d_in[4];
    const float* gw1   = (const float*)d_in[5];
    const float* gb1   = (const float*)d_in[6];
    const float* gw2   = (const float*)d_in[7];
    // d_in[8] = gate_b2: constant inside monotone sigmoid -> doesn't affect top-k

    float* ws = (float*)d_ws;
    int* flags = (int*)(ws + OFF_FLAGS);
    int* kidx  = (int*)(ws + OFF_KIDX);
    float* out = (float*)d_out;

    gate_kernel<<<B_ * S_ / 8, 256, 0, stream>>>(x, gw1, gb1, gw2, ws);
    rank_kernel<<<B_ * 128, 256, 0, stream>>>(ws + OFF_IMP, flags);
    emit_kernel<<<B_, 256, 0, stream>>>(flags, kidx);
    kv_kernel<<<dim3(51, B_), 256, 0, stream>>>(x, w_in, b_in, ws, kidx);
    // Q = x @ w_in[0:256]^T + b_in[0:256]
    gemm_kernel<<<dim3(B_ * S_ / 64, D_ / 64), 256, 0, stream>>>(x, w_in, b_in, ws + OFF_Q);
    attn_kernel<<<dim3(S_ / 32, H_, B_), 256, 0, stream>>>(ws, ws + OFF_AO);
    // out = AO @ w_out^T + b_out
    gemm_kernel<<<dim3(B_ * S_ / 64, D_ / 64), 256, 0, stream>>>(ws + OFF_AO, w_out, b_out, out);
}

// Round 3
// 167.291 us; speedup vs baseline: 1.4642x; 1.1102x over previous
//
#include <hip/hip_runtime.h>
#include <hip/hip_bf16.h>

// Problem constants
#define B_  4
#define S_  2048
#define D_  256
#define H_  8
#define HD_ 32
#define K_  204          // int(2048 * 0.1)
#define SCALE_ 0.17677669529663687f  // 1/sqrt(32)

// ---- workspace layout (float offsets) ----
#define OFF_IMP    0          // 8192 floats
#define OFF_KG     8192       // 208896 floats [B,H,K,hd]
#define OFF_VG     217088     // 208896 floats
#define OFF_FLAGS  425984     // 8192 ints
#define OFF_KIDX   434176     // 1024 ints
#define OFF_Q      435200     // 2097152 floats [B*S, D]
#define OFF_AO     2532352    // 2097152 floats [B*S, D]
// total ~4.63M floats = 18.5 MB

typedef __attribute__((ext_vector_type(8))) short short8v;
typedef __attribute__((ext_vector_type(4))) float f32x4;

static __device__ __forceinline__ unsigned short f2bf(float f) {
    unsigned int u = __float_as_uint(f);
    u += 0x7FFFu + ((u >> 16) & 1u);      // round-to-nearest-even
    return (unsigned short)(u >> 16);
}
static __device__ __forceinline__ float bf2f(unsigned short h) {
    return __uint_as_float((unsigned int)h << 16);
}
static __device__ __forceinline__ short8v pack_bf8(float4 a, float4 b) {
    short8v r;
    r[0]=(short)f2bf(a.x); r[1]=(short)f2bf(a.y); r[2]=(short)f2bf(a.z); r[3]=(short)f2bf(a.w);
    r[4]=(short)f2bf(b.x); r[5]=(short)f2bf(b.y); r[6]=(short)f2bf(b.z); r[7]=(short)f2bf(b.w);
    return r;
}
static __device__ __forceinline__ short8v ld_bf8(const unsigned short* p) {
    union { unsigned int u[4]; short8v v; } cv;
    const uint2 a  = *(const uint2*)(p);
    const uint2 b2 = *(const uint2*)(p + 4);
    cv.u[0] = a.x; cv.u[1] = a.y; cv.u[2] = b2.x; cv.u[3] = b2.y;
    return cv.v;
}
// 16 fp32 -> bf16 hi/lo planes (split precision), two 16B LDS stores each
static __device__ __forceinline__ void cvt_store16(
    unsigned short* hi, unsigned short* lo, const float4* v)
{
    #pragma unroll
    for (int q = 0; q < 2; ++q) {
        short8v h, l;
        #pragma unroll
        for (int e = 0; e < 2; ++e) {
            const float4 f = v[q*2 + e];
            const unsigned short h0 = f2bf(f.x), h1 = f2bf(f.y),
                                 h2 = f2bf(f.z), h3 = f2bf(f.w);
            h[e*4+0]=(short)h0; h[e*4+1]=(short)h1; h[e*4+2]=(short)h2; h[e*4+3]=(short)h3;
            l[e*4+0]=(short)f2bf(f.x - bf2f(h0));
            l[e*4+1]=(short)f2bf(f.y - bf2f(h1));
            l[e*4+2]=(short)f2bf(f.z - bf2f(h2));
            l[e*4+3]=(short)f2bf(f.w - bf2f(h3));
        }
        *(short8v*)(hi + q*8) = h;
        *(short8v*)(lo + q*8) = l;
    }
}

// ---------------- kernel 1: gate MLP -> importance logit ----------------
__global__ __launch_bounds__(256) void gate_kernel(
    const float* __restrict__ x, const float* __restrict__ gw1,
    const float* __restrict__ gb1, const float* __restrict__ gw2, float* ws)
{
    const int t0 = blockIdx.x * 8;
    const int tid = threadIdx.x;
    __shared__ __align__(16) float xs[8 * D_];
    __shared__ float hred[8 * 64];

    const float4* src = (const float4*)(x + (size_t)t0 * D_);
    ((float4*)xs)[tid]       = src[tid];
    ((float4*)xs)[tid + 256] = src[tid + 256];
    __syncthreads();

    const int c = tid & 3, f = tid >> 2;
    float4 wv[16];
    const float4* wr = (const float4*)(gw1 + (size_t)f * D_) + c;
    #pragma unroll
    for (int j = 0; j < 16; ++j) wv[j] = wr[j * 4];
    const float bb = gb1[f], g2 = gw2[f];

    #pragma unroll
    for (int tk = 0; tk < 8; ++tk) {
        const float4* xr = (const float4*)(xs + tk * D_) + c;
        float a = 0.0f;
        #pragma unroll
        for (int j = 0; j < 16; ++j) {
            float4 xv = xr[j * 4];
            a += wv[j].x*xv.x + wv[j].y*xv.y + wv[j].z*xv.z + wv[j].w*xv.w;
        }
        a += __shfl_xor(a, 1);
        a += __shfl_xor(a, 2);
        if (c == 0) hred[tk * 64 + f] = fmaxf(a + bb, 0.0f) * g2;
    }
    __syncthreads();

    const int tk = tid >> 5, ln = tid & 31;
    float s = hred[tk * 64 + ln] + hred[tk * 64 + ln + 32];
    #pragma unroll
    for (int o = 16; o; o >>= 1) s += __shfl_xor(s, o, 32);
    if (ln == 0) ws[OFF_IMP + t0 + tk] = s;
}

// ---------------- kernel 2a: exact rank -> kept flag (lax.top_k ties) ----------------
__global__ __launch_bounds__(256) void rank_kernel(const float* __restrict__ ws_imp, int* flags)
{
    const int b  = blockIdx.x >> 7;        // 128 i-chunks per batch
    const int ic = blockIdx.x & 127;
    const int tid = threadIdx.x;
    __shared__ __align__(16) float vs[S_];
    const float* src = ws_imp + b * S_;
    #pragma unroll
    for (int cc = 0; cc < S_/(256*4); ++cc)
        ((float4*)vs)[tid + cc*256] = ((const float4*)src)[tid + cc*256];
    __syncthreads();

    const int il = tid >> 4;               // 0..15 : which i of this block's 16
    const int c  = tid & 15;               // 0..15 : j-slice
    const int i  = ic * 16 + il;
    const float vi = vs[i];
    int gt = 0, eq = 0;
    const float4* v4 = (const float4*)vs + c * 32;   // this slice: 128 j's
    #pragma unroll 8
    for (int t = 0; t < 32; ++t) {
        const int j4 = (t + c) & 31;       // stagger start -> spread LDS banks
        float4 w = v4[j4];
        const int base = c * 128 + j4 * 4;
        gt += (w.x > vi); eq += (w.x == vi) && (base + 0 < i);
        gt += (w.y > vi); eq += (w.y == vi) && (base + 1 < i);
        gt += (w.z > vi); eq += (w.z == vi) && (base + 2 < i);
        gt += (w.w > vi); eq += (w.w == vi) && (base + 3 < i);
    }
    int r = gt + eq;
    r += __shfl_xor(r, 1);
    r += __shfl_xor(r, 2);
    r += __shfl_xor(r, 4);
    r += __shfl_xor(r, 8);
    if (c == 0) flags[b * S_ + i] = (r < K_) ? 1 : 0;
}

// ---------------- kernel 2b: scan flags -> compact sorted index list ----------------
__global__ __launch_bounds__(256) void emit_kernel(const int* __restrict__ flags, int* kidx)
{
    const int b = blockIdx.x;
    const int t = threadIdx.x;
    __shared__ int fl[S_];
    __shared__ int cs[256];
    const int* src = flags + b * S_;
    #pragma unroll
    for (int c = 0; c < S_/256; ++c) fl[t + c*256] = src[t + c*256];
    __syncthreads();

    int s = 0;
    #pragma unroll
    for (int c = 0; c < 8; ++c) s += fl[t*8 + c];
    cs[t] = s;
    __syncthreads();
    for (int off = 1; off < 256; off <<= 1) {
        int v = (t >= off) ? cs[t - off] : 0;
        __syncthreads();
        cs[t] += v;
        __syncthreads();
    }
    int pos = cs[t] - s;
    #pragma unroll
    for (int c = 0; c < 8; ++c) {
        int idx = t*8 + c;
        if (fl[idx]) { if (pos < K_) kidx[b * K_ + pos] = idx; ++pos; }
    }
}

// ---------------- kernel 3: K/V projection for kept keys ----------------
__global__ __launch_bounds__(256) void kv_kernel(
    const float* __restrict__ x, const float* __restrict__ w_in,
    const float* __restrict__ b_in, float* ws, const int* __restrict__ kidx)
{
    const int b = blockIdx.y, j0 = blockIdx.x * 4, tid = threadIdx.x;
    __shared__ __align__(16) float xs[4 * D_];
    __shared__ int toks[4];
    if (tid < 4) {
        int tk = kidx[b * K_ + j0 + tid];
        toks[tid] = min(max(tk, 0), S_ - 1);
    }
    __syncthreads();
    {
        const int kk = tid >> 6, l = tid & 63;
        ((float4*)xs)[kk * 64 + l] =
            ((const float4*)(x + ((size_t)b * S_ + toks[kk]) * D_))[l];
    }
    __syncthreads();

    const int c = tid & 3, f = tid >> 2;
    #pragma unroll 1
    for (int fg = 0; fg < 8; ++fg) {
        const int eh = fg * 64 + f;
        float4 wv[16];
        const float4* wr = (const float4*)(w_in + (size_t)(D_ + eh) * D_) + c;
        #pragma unroll
        for (int j = 0; j < 16; ++j) wv[j] = wr[j * 4];
        float a0 = 0, a1 = 0, a2 = 0, a3 = 0;
        #pragma unroll
        for (int j = 0; j < 16; ++j) {
            float4 w = wv[j];
            float4 x0 = ((const float4*)(xs + 0*D_))[c + j*4];
            float4 x1 = ((const float4*)(xs + 1*D_))[c + j*4];
            float4 x2 = ((const float4*)(xs + 2*D_))[c + j*4];
            float4 x3 = ((const float4*)(xs + 3*D_))[c + j*4];
            a0 += w.x*x0.x + w.y*x0.y + w.z*x0.z + w.w*x0.w;
            a1 += w.x*x1.x + w.y*x1.y + w.z*x1.z + w.w*x1.w;
            a2 += w.x*x2.x + w.y*x2.y + w.z*x2.z + w.w*x2.w;
            a3 += w.x*x3.x + w.y*x3.y + w.z*x3.z + w.w*x3.w;
        }
        a0 += __shfl_xor(a0, 1); a0 += __shfl_xor(a0, 2);
        a1 += __shfl_xor(a1, 1); a1 += __shfl_xor(a1, 2);
        a2 += __shfl_xor(a2, 1); a2 += __shfl_xor(a2, 2);
        a3 += __shfl_xor(a3, 1); a3 += __shfl_xor(a3, 2);
        if (c == 0) {
            const float bias = b_in[D_ + eh];
            const int isV = eh >> 8;
            const int ee = eh & 255;
            const int h = ee >> 5, d = ee & 31;
            float* dst = ws + (isV ? OFF_VG : OFF_KG) + ((b * H_ + h) * K_) * HD_ + d;
            dst[(j0 + 0) * HD_] = a0 + bias;
            dst[(j0 + 1) * HD_] = a1 + bias;
            dst[(j0 + 2) * HD_] = a2 + bias;
            dst[(j0 + 3) * HD_] = a3 + bias;
        }
    }
}

// ---------------- kernel 4: MFMA split-bf16 GEMM ----------------
// C[M,256] = A[M,256] * W[256,256]^T + bias, fp32-equivalent precision:
// A = Ah + Al, W = Wh + Wl (bf16 planes); C ~= Ah*Wh + Ah*Wl + Al*Wh (fp32 acc).
// BM=BN=64, BK=64, 4 waves each owning a 32x32 quadrant (2x2 of 16x16 MFMA tiles).
// LDS row stride 80 shorts (160B): 16B-aligned, fragment reads at baseline conflict level.
#define GSTR 80

__global__ __launch_bounds__(256) void gemm_kernel(
    const float* __restrict__ A, const float* __restrict__ W,
    const float* __restrict__ bias, float* __restrict__ C)
{
    __shared__ __align__(16) unsigned short Ash[64 * GSTR];
    __shared__ __align__(16) unsigned short Asl[64 * GSTR];
    __shared__ __align__(16) unsigned short Bsh[64 * GSTR];
    __shared__ __align__(16) unsigned short Bsl[64 * GSTR];

    const int tid = threadIdx.x;
    const int m0 = blockIdx.x * 64, n0 = blockIdx.y * 64;
    const int lane = tid & 63, w = tid >> 6;
    const int c = lane & 15, g = lane >> 4;
    const int mq = w >> 1, nq = w & 1;

    const f32x4 zf = {0.0f, 0.0f, 0.0f, 0.0f};
    f32x4 acc[2][2] = {{zf, zf}, {zf, zf}};

    // staging: thread -> (row 0..63, 16-float segment 0..3)
    const int srow = tid >> 2, sseg = tid & 3;
    const float* Ap = A + (size_t)(m0 + srow) * D_ + sseg * 16;
    const float* Wp = W + (size_t)(n0 + srow) * D_ + sseg * 16;

    float4 ar[4], br[4];
    #pragma unroll
    for (int j = 0; j < 4; ++j) { ar[j] = ((const float4*)Ap)[j]; br[j] = ((const float4*)Wp)[j]; }

    for (int k0 = 0; k0 < D_; k0 += 64) {
        __syncthreads();                      // previous compute's LDS reads done
        cvt_store16(&Ash[srow*GSTR + sseg*16], &Asl[srow*GSTR + sseg*16], ar);
        cvt_store16(&Bsh[srow*GSTR + sseg*16], &Bsl[srow*GSTR + sseg*16], br);
        __syncthreads();                      // writes visible
        if (k0 + 64 < D_) {                   // prefetch next K-tile (hidden under MFMA)
            #pragma unroll
            for (int j = 0; j < 4; ++j) {
                ar[j] = ((const float4*)(Ap + k0 + 64))[j];
                br[j] = ((const float4*)(Wp + k0 + 64))[j];
            }
        }
        #pragma unroll
        for (int ks = 0; ks < 2; ++ks) {
            short8v am[2][2], bm[2][2];       // [tile][hi/lo]
            #pragma unroll
            for (int t = 0; t < 2; ++t) {
                const int ra = (mq*32 + t*16 + c) * GSTR + ks*32 + g*8;
                am[t][0] = *(const short8v*)&Ash[ra];
                am[t][1] = *(const short8v*)&Asl[ra];
                const int rb = (nq*32 + t*16 + c) * GSTR + ks*32 + g*8;
                bm[t][0] = *(const short8v*)&Bsh[rb];
                bm[t][1] = *(const short8v*)&Bsl[rb];
            }
            #pragma unroll
            for (int mt = 0; mt < 2; ++mt)
                #pragma unroll
                for (int nt = 0; nt < 2; ++nt) {
                    acc[mt][nt] = __builtin_amdgcn_mfma_f32_16x16x32_bf16(am[mt][0], bm[nt][0], acc[mt][nt], 0, 0, 0);
                    acc[mt][nt] = __builtin_amdgcn_mfma_f32_16x16x32_bf16(am[mt][0], bm[nt][1], acc[mt][nt], 0, 0, 0);
                    acc[mt][nt] = __builtin_amdgcn_mfma_f32_16x16x32_bf16(am[mt][1], bm[nt][0], acc[mt][nt], 0, 0, 0);
                }
        }
    }
    // epilogue: D layout col = lane&15, row = (lane>>4)*4 + r
    #pragma unroll
    for (int nt = 0; nt < 2; ++nt) {
        const int n = n0 + nq*32 + nt*16 + c;
        const float bv = bias[n];
        #pragma unroll
        for (int mt = 0; mt < 2; ++mt) {
            const int m = m0 + mq*32 + mt*16 + g*4;
            #pragma unroll
            for (int r = 0; r < 4; ++r)
                C[(size_t)(m + r) * D_ + n] = acc[mt][nt][r] + bv;
        }
    }
}

// ---------------- kernel 5: attention core (MFMA bf16, fp32 accum) ----------------
#define PSTR 228   // P row stride (bf16 elems)
#define VSTR 228   // V^T row stride

__global__ __launch_bounds__(256) void attn_kernel(const float* __restrict__ ws, float* __restrict__ ao)
{
    const int b = blockIdx.z, h = blockIdx.y, q0 = blockIdx.x * 32;
    const int tid = threadIdx.x;
    const int lane = tid & 63, w = tid >> 6;
    const int c = lane & 15, g = lane >> 4;

    __shared__ __align__(16) unsigned short Pl[32 * PSTR];    // P[q][j] bf16
    __shared__ __align__(16) unsigned short VTl[32 * VSTR];   // V^T[d][j] bf16
    __shared__ float redl[4 * 32];
    __shared__ float invl[32];

    const float* KGb = ws + OFF_KG + (size_t)(b * H_ + h) * K_ * HD_;
    const float* VGb = ws + OFF_VG + (size_t)(b * H_ + h) * K_ * HD_;

    // ---- stage V^T (bf16) into LDS; zero pad regions ----
    for (int i = tid; i < K_ * 8; i += 256) {
        const int j = i >> 3, dc = i & 7;
        const float4 v = ((const float4*)VGb)[i];
        VTl[(dc*4+0)*VSTR + j] = f2bf(v.x);
        VTl[(dc*4+1)*VSTR + j] = f2bf(v.y);
        VTl[(dc*4+2)*VSTR + j] = f2bf(v.z);
        VTl[(dc*4+3)*VSTR + j] = f2bf(v.w);
    }
    {   // P pad: j = 208..223 for all 32 q rows
        const int q = tid >> 3, cc = tid & 7;
        *(unsigned int*)&Pl[q * PSTR + 208 + cc * 2] = 0u;
    }
    for (int i = tid; i < 32 * 20; i += 256) {   // VT pad: j = 204..223
        VTl[(i / 20) * VSTR + 204 + (i % 20)] = 0;
    }

    // ---- QK^T via MFMA: wave w handles j-tiles {w, w+4, w+8, (w+12)} ----
    short8v qa[2];
    #pragma unroll
    for (int qt = 0; qt < 2; ++qt) {
        const float* qp = ws + OFF_Q + (size_t)(b * S_ + q0 + qt*16 + c) * D_ + h * HD_ + g * 8;
        qa[qt] = pack_bf8(*(const float4*)qp, *(const float4*)(qp + 4));
    }
    const int njt = (w == 0) ? 4 : 3;
    f32x4 acc[2][4];
    const f32x4 zf = {0.0f, 0.0f, 0.0f, 0.0f};
    #pragma unroll
    for (int qt = 0; qt < 2; ++qt)
        #pragma unroll
        for (int t = 0; t < 4; ++t) acc[qt][t] = zf;

    for (int t = 0; t < njt; ++t) {
        const int jt = w + 4 * t;
        const int jc = min(jt * 16 + c, K_ - 1);
        const float* kp = KGb + (size_t)jc * HD_ + g * 8;
        const short8v kb = pack_bf8(*(const float4*)kp, *(const float4*)(kp + 4));
        acc[0][t] = __builtin_amdgcn_mfma_f32_16x16x32_bf16(qa[0], kb, acc[0][t], 0, 0, 0);
        acc[1][t] = __builtin_amdgcn_mfma_f32_16x16x32_bf16(qa[1], kb, acc[1][t], 0, 0, 0);
    }

    // exp (fp32), write P (bf16), accumulate row-sums
    float rs[2][4] = {{0,0,0,0},{0,0,0,0}};
    for (int t = 0; t < njt; ++t) {
        const int jg = (w + 4 * t) * 16 + c;
        const bool val = (jg < K_);
        #pragma unroll
        for (int qt = 0; qt < 2; ++qt) {
            #pragma unroll
            for (int r = 0; r < 4; ++r) {
                const float e = val ? __expf(acc[qt][t][r] * SCALE_) : 0.0f;
                rs[qt][r] += e;
                Pl[(qt*16 + g*4 + r) * PSTR + jg] = f2bf(e);
            }
        }
    }
    #pragma unroll
    for (int qt = 0; qt < 2; ++qt)
        #pragma unroll
        for (int r = 0; r < 4; ++r) {
            float s = rs[qt][r];
            s += __shfl_xor(s, 1); s += __shfl_xor(s, 2);
            s += __shfl_xor(s, 4); s += __shfl_xor(s, 8);
            if (c == 0) redl[w * 32 + qt*16 + g*4 + r] = s;
        }

    __syncthreads();
    if (tid < 32)
        invl[tid] = 1.0f / (redl[tid] + redl[32 + tid] + redl[64 + tid] + redl[96 + tid]);
    __syncthreads();

    // ---- PV: O^T = V^T * P^T; wave w -> quadrant (dt = w>>1, qt2 = w&1) ----
    const int dt = w >> 1, qt2 = w & 1;
    f32x4 o = zf;
    const unsigned short* vb = &VTl[(dt*16 + c) * VSTR];
    const unsigned short* pb = &Pl[(qt2*16 + c) * PSTR];
    #pragma unroll
    for (int kt = 0; kt < 7; ++kt) {
        const short8v av = ld_bf8(vb + kt*32 + g*8);
        const short8v bv = ld_bf8(pb + kt*32 + g*8);
        o = __builtin_amdgcn_mfma_f32_16x16x32_bf16(av, bv, o, 0, 0, 0);
    }
    const float iv = invl[qt2*16 + c];
    float4 r4; r4.x = o[0]*iv; r4.y = o[1]*iv; r4.z = o[2]*iv; r4.w = o[3]*iv;
    *(float4*)(ao + (size_t)(b * S_ + q0 + qt2*16 + c) * D_ + h * HD_ + dt*16 + g*4) = r4;
}

extern "C" void kernel_launch(void* const* d_in, const int* in_sizes, int n_in,
                              void* d_out, int out_size, void* d_ws, size_t ws_size,
                              hipStream_t stream)
{
    const float* x     = (const float*)d_in[0];
    const float* w_in  = (const float*)d_in[1];
    const float* b_in  = (const float*)d_in[2];
    const float* w_out = (const float*)d_in[3];
    const float* b_out = (const float*)d_in[4];
    const float* gw1   = (const float*)d_in[5];
    const float* gb1   = (const float*)d_in[6];
    const float* gw2   = (const float*)d_in[7];
    // d_in[8] = gate_b2: constant inside monotone sigmoid -> doesn't affect top-k

    float* ws = (float*)d_ws;
    int* flags = (int*)(ws + OFF_FLAGS);
    int* kidx  = (int*)(ws + OFF_KIDX);
    float* out = (float*)d_out;

    gate_kernel<<<B_ * S_ / 8, 256, 0, stream>>>(x, gw1, gb1, gw2, ws);
    rank_kernel<<<B_ * 128, 256, 0, stream>>>(ws + OFF_IMP, flags);
    emit_kernel<<<B_, 256, 0, stream>>>(flags, kidx);
    kv_kernel<<<dim3(51, B_), 256, 0, stream>>>(x, w_in, b_in, ws, kidx);
    // Q = x @ w_in[0:256]^T + b_in[0:256]
    gemm_kernel<<<dim3(B_ * S_ / 64, D_ / 64), 256, 0, stream>>>(x, w_in, b_in, ws + OFF_Q);
    attn_kernel<<<dim3(S_ / 32, H_, B_), 256, 0, stream>>>(ws, ws + OFF_AO);
    // out = AO @ w_out^T + b_out
    gemm_kernel<<<dim3(B_ * S_ / 64, D_ / 64), 256, 0, stream>>>(ws + OFF_AO, w_out, b_out, out);
}